// Round 4
// baseline (395.218 us; speedup 1.0000x reference)
//
#include <hip/hip_runtime.h>
#include <stdint.h>

// GeometricBilinearLayer: B=32,N=1024,Cin=64,Cout=64,H=32, PGA(3,0,1). f32 I/O.
// R8 = R7 with compile fix: nontemporal stores use ext_vector f32x4 (clang builtin
// rejects HIP_vector_type float4*).
// R7: cross-tile software pipeline (T14 async-STAGE split).
//   - NT=2 tiles per block; next tile's x issued as 16x global_load_dwordx4 into regs
//     right after the xT-read barrier, consumed (convert+LDS write) after the fT-read
//     barrier => ~900cy HBM latency hidden under phase2 VALU + phase3 MFMA.
//   - staging loads float4 (16 VMEM/lane vs 64 scalar), b128 LDS writes, chunk-uniform.
//   - nontemporal out stores (preserve L3 residency of x).
//   - launch_bounds(256,3): cap VGPR ~170 -> 3 blocks/CU (LDS 32KB would allow 5).

#define BN 32768
#define NT 2
#define GRID (BN / 16 / NT)   // 1024

typedef __attribute__((ext_vector_type(2))) _Float16 h2;   // v_pk_* operand
typedef __attribute__((ext_vector_type(8))) _Float16 h8;   // f16 MFMA fragment (4 VGPR)
typedef __attribute__((ext_vector_type(4))) float f32x4;

#define MFMA_F16 __builtin_amdgcn_mfma_f32_16x16x32_f16

__device__ __forceinline__ h2 pk(float a, float b) {
  return (h2)__builtin_amdgcn_cvt_pkrtz(a, b);   // lo = a, hi = b
}

// ---------- compile-time Clifford tables (verified by R3/R4 pass) ----------
constexpr int IDX2MASK[16] = {0,1,2,4,8,3,5,9,6,10,12,7,11,13,14,15};
constexpr int MASK2IDX[16] = {0,1,2,5,3,6,8,11,4,7,9,12,10,13,14,15};

struct MulRes { float s; int idx; };

constexpr MulRes blade_mul(int ia, int ib) {
  int arr[8] = {0,0,0,0,0,0,0,0}; int n = 0;
  for (int e = 0; e < 4; ++e) if ((IDX2MASK[ia] >> e) & 1) arr[n++] = e;
  for (int e = 0; e < 4; ++e) if ((IDX2MASK[ib] >> e) & 1) arr[n++] = e;
  float sign = 1.0f;
  bool sw = true;
  while (sw) {
    sw = false;
    for (int j = 0; j + 1 < n; ++j)
      if (arr[j] > arr[j+1]) { int t = arr[j]; arr[j] = arr[j+1]; arr[j+1] = t; sign = -sign; sw = true; }
  }
  int mask = 0; int j = 0;
  while (j < n) {
    if (j + 1 < n && arr[j] == arr[j+1]) { if (arr[j] == 0) sign = 0.0f; j += 2; }  // e0^2 = 0
    else { mask |= 1 << arr[j]; ++j; }
  }
  return MulRes{sign, MASK2IDX[mask]};
}

constexpr float dual_sign(int i) {
  return blade_mul(i, MASK2IDX[15 ^ IDX2MASK[i]]).s;
}

struct Tab { float s[16][16]; int k[16][16]; };

constexpr Tab make_gp() {
  Tab t{};
  for (int i = 0; i < 16; ++i)
    for (int j = 0; j < 16; ++j) { MulRes r = blade_mul(i, j); t.s[i][j] = r.s; t.k[i][j] = r.idx; }
  return t;
}

constexpr Tab make_join() {
  Tab t{};
  for (int i = 0; i < 16; ++i)
    for (int j = 0; j < 16; ++j) {
      int ma = 15 ^ IDX2MASK[i], mb = 15 ^ IDX2MASK[j];
      if (ma & mb) { t.s[i][j] = 0.0f; t.k[i][j] = 0; continue; }
      int ia = MASK2IDX[ma], ib = MASK2IDX[mb];
      MulRes w = blade_mul(ia, ib);
      int kk = MASK2IDX[15 ^ IDX2MASK[w.idx]];
      t.s[i][j] = dual_sign(i) * dual_sign(j) * w.s * dual_sign(kk);
      t.k[i][j] = kk;
    }
  return t;
}

constexpr Tab GPT = make_gp();
constexpr Tab JNT = make_join();
constexpr int GRADE[16] = {0,1,1,1,1,2,2,2,2,2,2,3,3,3,3,4};
constexpr int GSTART[6] = {0,1,5,11,15,16};   // blade idx is grade-ordered

// per-output-blade regrouped bilinear tables (same terms, k-major)
struct KTab { int cnt[16]; int ti[16][16]; int tj[16][16]; float ts[16][16]; };
constexpr KTab make_ktab(const Tab& t) {
  KTab b{};
  for (int i = 0; i < 16; ++i)
    for (int j = 0; j < 16; ++j) {
      float s = t.s[i][j];
      if (s != 0.f) { int k = t.k[i][j]; int m = b.cnt[k]; b.cnt[k] = m + 1;
                      b.ti[k][m] = i; b.tj[k][m] = j; b.ts[k][m] = s; }
    }
  return b;
}
constexpr KTab GPK = make_ktab(GPT);   // 192 terms, 12 per k
constexpr KTab JNK = make_ktab(JNT);   // 81 terms, <=16 per k

// ---------- LDS layout: 16 planes x 16 tok x 64 shorts, XOR-swizzled 16B chunks ----------
// short-index within plane row swizzled: s ^ (((k + tok) & 7) << 3).
__device__ __forceinline__ int lds_sh(int k, int tok, int s) {
  return k * 1024 + tok * 64 + (s ^ (((k + tok) & 7) << 3));
}

// ---------- f16 weight tables (module-scope; rewritten every launch) ----------
__device__ __align__(16) short g_wpre_h[4 * 5 * 32 * 64];   // 40960 shorts
__device__ __align__(16) short g_wfin_h[5 * 64 * 64];       // 20480 shorts

__global__ void cast_weights(const float* __restrict__ wpx, const float* __restrict__ wpy,
                             const float* __restrict__ wjx, const float* __restrict__ wjy,
                             const float* __restrict__ wf) {
  int idx = blockIdx.x * 256 + threadIdx.x;
  if (idx < 40960) {
    int which = idx / 10240, r = idx % 10240;
    const float* src = (which == 0) ? wpx : (which == 1) ? wpy : (which == 2) ? wjx : wjy;
    _Float16 h = (_Float16)src[r];
    g_wpre_h[idx] = __builtin_bit_cast(short, h);
  } else if (idx < 40960 + 20480) {
    int r = idx - 40960;
    _Float16 h = (_Float16)wf[r];
    g_wfin_h[r] = __builtin_bit_cast(short, h);
  }
}

// convert prefetched f32x4 regs -> f16 pairs -> swizzled b128 LDS writes.
// thread (tok, kq, iq) holds pf[ii] = x[t][iq*16+ii][kq*4 .. kq*4+3], ii=0..15.
__device__ __forceinline__ void stage_write(short* ldsb, int tok, int kq, int iq,
                                            const f32x4* pf) {
  #pragma unroll
  for (int jk = 0; jk < 4; ++jk) {
    const int k = kq * 4 + jk;
    uint32_t c0 = __builtin_bit_cast(uint32_t, pk(pf[0][jk],  pf[1][jk]));
    uint32_t c1 = __builtin_bit_cast(uint32_t, pk(pf[2][jk],  pf[3][jk]));
    uint32_t c2 = __builtin_bit_cast(uint32_t, pk(pf[4][jk],  pf[5][jk]));
    uint32_t c3 = __builtin_bit_cast(uint32_t, pk(pf[6][jk],  pf[7][jk]));
    uint32_t c4 = __builtin_bit_cast(uint32_t, pk(pf[8][jk],  pf[9][jk]));
    uint32_t c5 = __builtin_bit_cast(uint32_t, pk(pf[10][jk], pf[11][jk]));
    uint32_t c6 = __builtin_bit_cast(uint32_t, pk(pf[12][jk], pf[13][jk]));
    uint32_t c7 = __builtin_bit_cast(uint32_t, pk(pf[14][jk], pf[15][jk]));
    *(uint4*)&ldsb[lds_sh(k, tok, iq * 16)]     = make_uint4(c0, c1, c2, c3);
    *(uint4*)&ldsb[lds_sh(k, tok, iq * 16 + 8)] = make_uint4(c4, c5, c6, c7);
  }
}

// ---------- main kernel ----------
__global__ __launch_bounds__(256, 3) void gbl_kernel(
    const float* __restrict__ x,     // [BN][64][16]
    const float* __restrict__ ref,   // [BN][16]
    float* __restrict__ out)         // [BN][64][16]
{
  // one buffer, two lives per tile: xT[blade][tok][i] f16, then fT[blade][tok][cc] f16
  __shared__ __align__(16) short ldsb[16 * 1024];   // 32768 B

  const int tid  = threadIdx.x;
  const int w    = tid >> 6;        // wave 0..3
  const int lane = tid & 63;
  const int n    = lane & 15;       // MFMA free-dim lane index
  const int q    = lane >> 4;       // quad
  const int br   = w >> 1, nth = w & 1;   // branch (0=prod,1=join), c-half

  // staging thread mapping: tok(4b) | kq(2b) | iq(2b)
  const int stok = tid >> 4;
  const int skq  = (tid >> 2) & 3;
  const int siq  = tid & 3;

  const int tile0 = blockIdx.x * NT;

  f32x4 pf[16];          // prefetched x (one tile's worth per thread)
  float refc[4], refn[4];

  // ---- prologue: load + stage tile 0 ----
  {
    const float* base = x + (size_t)(tile0 * 16 + stok) * 1024 + (siq * 16) * 16 + skq * 4;
    #pragma unroll
    for (int ii = 0; ii < 16; ++ii) pf[ii] = *(const f32x4*)(base + ii * 16);
    if (br == 1) {
      #pragma unroll
      for (int r = 0; r < 4; ++r) refc[r] = ref[(size_t)(tile0 * 16 + 4 * q + r) * 16 + 15];
    }
  }
  stage_write(ldsb, stok, skq, siq, pf);

  for (int it = 0; it < NT; ++it) {
    const int t0 = (tile0 + it) * 16;
    __syncthreads();                                   // [B] xT ready

    // ---- Phase 1: stage-A pre-equilins via f16 MFMA, packed-f16 results ----
    h2 pxh[16][2], pyh[16][2];
    #pragma unroll
    for (int g = 0; g < 5; ++g) {
      const short* bx = &g_wpre_h[(((br * 2 + 0) * 5 + g) * 32 + nth * 16 + n) * 64 + q * 8];
      const short* by = &g_wpre_h[(((br * 2 + 1) * 5 + g) * 32 + nth * 16 + n) * 64 + q * 8];
      h8 Bx0 = *(const h8*)(bx), Bx1 = *(const h8*)(bx + 32);
      h8 By0 = *(const h8*)(by), By1 = *(const h8*)(by + 32);
      #pragma unroll
      for (int kb = GSTART[g]; kb < GSTART[g + 1]; ++kb) {
        h8 a0 = *(const h8*)&ldsb[lds_sh(kb, n, q * 8)];
        h8 a1 = *(const h8*)&ldsb[lds_sh(kb, n, 32 + q * 8)];
        f32x4 ax = {0.f, 0.f, 0.f, 0.f};
        ax = MFMA_F16(a0, Bx0, ax, 0, 0, 0);
        ax = MFMA_F16(a1, Bx1, ax, 0, 0, 0);
        pxh[kb][0] = pk(ax[0], ax[1]);
        pxh[kb][1] = pk(ax[2], ax[3]);
        f32x4 ay = {0.f, 0.f, 0.f, 0.f};
        ay = MFMA_F16(a0, By0, ay, 0, 0, 0);
        ay = MFMA_F16(a1, By1, ay, 0, 0, 0);
        pyh[kb][0] = pk(ay[0], ay[1]);
        pyh[kb][1] = pk(ay[2], ay[3]);
      }
    }
    __syncthreads();                                   // [D] all xT reads done

    // ---- issue next tile's loads; latency hides under phase 2 + phase 3 ----
    if (it + 1 < NT) {
      const float* base = x + (size_t)((tile0 + it + 1) * 16 + stok) * 1024
                            + (siq * 16) * 16 + skq * 4;
      #pragma unroll
      for (int ii = 0; ii < 16; ++ii) pf[ii] = *(const f32x4*)(base + ii * 16);
      if (br == 1) {
        #pragma unroll
        for (int r = 0; r < 4; ++r)
          refn[r] = ref[(size_t)((tile0 + it + 1) * 16 + 4 * q + r) * 16 + 15];
      }
    }

    // ---- Phase 2: in-register bilinear (packed f16) -> fT ----
    {
      h2 rv0, rv1;
      if (br == 1) { rv0 = pk(refc[0], refc[1]); rv1 = pk(refc[2], refc[3]); }
      const int cg = w * 16 + n;
      #pragma unroll
      for (int k = 0; k < 16; ++k) {
        h2 a0 = (_Float16)0.0f, a1 = (_Float16)0.0f;
        if (br == 0) {
          #pragma unroll
          for (int m = 0; m < 16; ++m) {
            if (m < GPK.cnt[k]) {
              const int i = GPK.ti[k][m], j = GPK.tj[k][m];
              if (GPK.ts[k][m] < 0.f) { a0 -= pxh[i][0] * pyh[j][0]; a1 -= pxh[i][1] * pyh[j][1]; }
              else                    { a0 += pxh[i][0] * pyh[j][0]; a1 += pxh[i][1] * pyh[j][1]; }
            }
          }
        } else {
          #pragma unroll
          for (int m = 0; m < 16; ++m) {
            if (m < JNK.cnt[k]) {
              const int i = JNK.ti[k][m], j = JNK.tj[k][m];
              if (JNK.ts[k][m] < 0.f) { a0 -= pxh[i][0] * pyh[j][0]; a1 -= pxh[i][1] * pyh[j][1]; }
              else                    { a0 += pxh[i][0] * pyh[j][0]; a1 += pxh[i][1] * pyh[j][1]; }
            }
          }
          a0 *= rv0; a1 *= rv1;
        }
        uint32_t u0 = __builtin_bit_cast(uint32_t, a0);
        uint32_t u1 = __builtin_bit_cast(uint32_t, a1);
        ldsb[lds_sh(k, 4 * q + 0, cg)] = (short)(u0 & 0xffffu);
        ldsb[lds_sh(k, 4 * q + 1, cg)] = (short)(u0 >> 16);
        ldsb[lds_sh(k, 4 * q + 2, cg)] = (short)(u1 & 0xffffu);
        ldsb[lds_sh(k, 4 * q + 3, cg)] = (short)(u1 >> 16);
      }
    }
    __syncthreads();                                   // [F] fT ready

    // ---- Phase 3: final equilin via f16 MFMA; full D[16], 64B-contiguous nt stores ----
    {
      const int o = w * 16 + n;
      f32x4 D[16];
      h8 BF0, BF1;
      #pragma unroll
      for (int kb = 0; kb < 16; ++kb) {
        if (kb == 0 || kb == 1 || kb == 5 || kb == 11 || kb == 15) {   // grade boundary
          const short* bf = &g_wfin_h[(GRADE[kb] * 64 + o) * 64 + q * 8];
          BF0 = *(const h8*)(bf);
          BF1 = *(const h8*)(bf + 32);
        }
        h8 a0 = *(const h8*)&ldsb[lds_sh(kb, n, q * 8)];
        h8 a1 = *(const h8*)&ldsb[lds_sh(kb, n, 32 + q * 8)];
        f32x4 acc = {0.f, 0.f, 0.f, 0.f};
        acc = MFMA_F16(a0, BF0, acc, 0, 0, 0);
        acc = MFMA_F16(a1, BF1, acc, 0, 0, 0);
        D[kb] = acc;
      }
      #pragma unroll
      for (int r = 0; r < 4; ++r) {
        const int t = t0 + 4 * q + r;
        f32x4* op = (f32x4*)(out + (size_t)t * 1024 + o * 16);
        f32x4 s0 = {D[0][r],  D[1][r],  D[2][r],  D[3][r]};
        f32x4 s1 = {D[4][r],  D[5][r],  D[6][r],  D[7][r]};
        f32x4 s2 = {D[8][r],  D[9][r],  D[10][r], D[11][r]};
        f32x4 s3 = {D[12][r], D[13][r], D[14][r], D[15][r]};
        __builtin_nontemporal_store(s0, op + 0);
        __builtin_nontemporal_store(s1, op + 1);
        __builtin_nontemporal_store(s2, op + 2);
        __builtin_nontemporal_store(s3, op + 3);
      }
    }

    // ---- stage next tile's xT (buffer free only after all fT reads done) ----
    if (it + 1 < NT) {
      __syncthreads();                                 // [H] fT reads done
      stage_write(ldsb, stok, skq, siq, pf);
      if (br == 1) {
        #pragma unroll
        for (int r = 0; r < 4; ++r) refc[r] = refn[r];
      }
    }
  }
}

extern "C" void kernel_launch(void* const* d_in, const int* in_sizes, int n_in,
                              void* d_out, int out_size, void* d_ws, size_t ws_size,
                              hipStream_t stream) {
  const float* x   = (const float*)d_in[0];
  const float* ref = (const float*)d_in[1];
  const float* wpx = (const float*)d_in[2];
  const float* wpy = (const float*)d_in[3];
  const float* wjx = (const float*)d_in[4];
  const float* wjy = (const float*)d_in[5];
  const float* wfi = (const float*)d_in[6];

  cast_weights<<<240, 256, 0, stream>>>(wpx, wpy, wjx, wjy, wfi);
  gbl_kernel<<<GRID, 256, 0, stream>>>(x, ref, (float*)d_out);
}

// Round 5
// 368.704 us; speedup vs baseline: 1.0719x; 1.0719x over previous
//
#include <hip/hip_runtime.h>
#include <stdint.h>

// GeometricBilinearLayer: B=32,N=1024,Cin=64,Cout=64,H=32, PGA(3,0,1). f32 I/O.
// R9 = R8 minus nontemporal stores (R8 post-mortem: nt stores bypassed L2
// write-combining -> 2.9x WRITE_SIZE + RMW fetch amplification = whole regression).
// Plain f32x4 stores restore R6's 1.0x write path; keep the NT=2 cross-tile
// pipeline (T14) + f32x4 staging loads.

#define BN 32768
#define NT 2
#define GRID (BN / 16 / NT)   // 1024

typedef __attribute__((ext_vector_type(2))) _Float16 h2;   // v_pk_* operand
typedef __attribute__((ext_vector_type(8))) _Float16 h8;   // f16 MFMA fragment (4 VGPR)
typedef __attribute__((ext_vector_type(4))) float f32x4;

#define MFMA_F16 __builtin_amdgcn_mfma_f32_16x16x32_f16

__device__ __forceinline__ h2 pk(float a, float b) {
  return (h2)__builtin_amdgcn_cvt_pkrtz(a, b);   // lo = a, hi = b
}

// ---------- compile-time Clifford tables (verified by R3/R4 pass) ----------
constexpr int IDX2MASK[16] = {0,1,2,4,8,3,5,9,6,10,12,7,11,13,14,15};
constexpr int MASK2IDX[16] = {0,1,2,5,3,6,8,11,4,7,9,12,10,13,14,15};

struct MulRes { float s; int idx; };

constexpr MulRes blade_mul(int ia, int ib) {
  int arr[8] = {0,0,0,0,0,0,0,0}; int n = 0;
  for (int e = 0; e < 4; ++e) if ((IDX2MASK[ia] >> e) & 1) arr[n++] = e;
  for (int e = 0; e < 4; ++e) if ((IDX2MASK[ib] >> e) & 1) arr[n++] = e;
  float sign = 1.0f;
  bool sw = true;
  while (sw) {
    sw = false;
    for (int j = 0; j + 1 < n; ++j)
      if (arr[j] > arr[j+1]) { int t = arr[j]; arr[j] = arr[j+1]; arr[j+1] = t; sign = -sign; sw = true; }
  }
  int mask = 0; int j = 0;
  while (j < n) {
    if (j + 1 < n && arr[j] == arr[j+1]) { if (arr[j] == 0) sign = 0.0f; j += 2; }  // e0^2 = 0
    else { mask |= 1 << arr[j]; ++j; }
  }
  return MulRes{sign, MASK2IDX[mask]};
}

constexpr float dual_sign(int i) {
  return blade_mul(i, MASK2IDX[15 ^ IDX2MASK[i]]).s;
}

struct Tab { float s[16][16]; int k[16][16]; };

constexpr Tab make_gp() {
  Tab t{};
  for (int i = 0; i < 16; ++i)
    for (int j = 0; j < 16; ++j) { MulRes r = blade_mul(i, j); t.s[i][j] = r.s; t.k[i][j] = r.idx; }
  return t;
}

constexpr Tab make_join() {
  Tab t{};
  for (int i = 0; i < 16; ++i)
    for (int j = 0; j < 16; ++j) {
      int ma = 15 ^ IDX2MASK[i], mb = 15 ^ IDX2MASK[j];
      if (ma & mb) { t.s[i][j] = 0.0f; t.k[i][j] = 0; continue; }
      int ia = MASK2IDX[ma], ib = MASK2IDX[mb];
      MulRes w = blade_mul(ia, ib);
      int kk = MASK2IDX[15 ^ IDX2MASK[w.idx]];
      t.s[i][j] = dual_sign(i) * dual_sign(j) * w.s * dual_sign(kk);
      t.k[i][j] = kk;
    }
  return t;
}

constexpr Tab GPT = make_gp();
constexpr Tab JNT = make_join();
constexpr int GRADE[16] = {0,1,1,1,1,2,2,2,2,2,2,3,3,3,3,4};
constexpr int GSTART[6] = {0,1,5,11,15,16};   // blade idx is grade-ordered

// per-output-blade regrouped bilinear tables (same terms, k-major)
struct KTab { int cnt[16]; int ti[16][16]; int tj[16][16]; float ts[16][16]; };
constexpr KTab make_ktab(const Tab& t) {
  KTab b{};
  for (int i = 0; i < 16; ++i)
    for (int j = 0; j < 16; ++j) {
      float s = t.s[i][j];
      if (s != 0.f) { int k = t.k[i][j]; int m = b.cnt[k]; b.cnt[k] = m + 1;
                      b.ti[k][m] = i; b.tj[k][m] = j; b.ts[k][m] = s; }
    }
  return b;
}
constexpr KTab GPK = make_ktab(GPT);   // 192 terms, 12 per k
constexpr KTab JNK = make_ktab(JNT);   // 81 terms, <=16 per k

// ---------- LDS layout: 16 planes x 16 tok x 64 shorts, XOR-swizzled 16B chunks ----------
// short-index within plane row swizzled: s ^ (((k + tok) & 7) << 3).
__device__ __forceinline__ int lds_sh(int k, int tok, int s) {
  return k * 1024 + tok * 64 + (s ^ (((k + tok) & 7) << 3));
}

// ---------- f16 weight tables (module-scope; rewritten every launch) ----------
__device__ __align__(16) short g_wpre_h[4 * 5 * 32 * 64];   // 40960 shorts
__device__ __align__(16) short g_wfin_h[5 * 64 * 64];       // 20480 shorts

__global__ void cast_weights(const float* __restrict__ wpx, const float* __restrict__ wpy,
                             const float* __restrict__ wjx, const float* __restrict__ wjy,
                             const float* __restrict__ wf) {
  int idx = blockIdx.x * 256 + threadIdx.x;
  if (idx < 40960) {
    int which = idx / 10240, r = idx % 10240;
    const float* src = (which == 0) ? wpx : (which == 1) ? wpy : (which == 2) ? wjx : wjy;
    _Float16 h = (_Float16)src[r];
    g_wpre_h[idx] = __builtin_bit_cast(short, h);
  } else if (idx < 40960 + 20480) {
    int r = idx - 40960;
    _Float16 h = (_Float16)wf[r];
    g_wfin_h[r] = __builtin_bit_cast(short, h);
  }
}

// convert prefetched f32x4 regs -> f16 pairs -> swizzled b128 LDS writes.
// thread (tok, kq, iq) holds pf[ii] = x[t][iq*16+ii][kq*4 .. kq*4+3], ii=0..15.
__device__ __forceinline__ void stage_write(short* ldsb, int tok, int kq, int iq,
                                            const f32x4* pf) {
  #pragma unroll
  for (int jk = 0; jk < 4; ++jk) {
    const int k = kq * 4 + jk;
    uint32_t c0 = __builtin_bit_cast(uint32_t, pk(pf[0][jk],  pf[1][jk]));
    uint32_t c1 = __builtin_bit_cast(uint32_t, pk(pf[2][jk],  pf[3][jk]));
    uint32_t c2 = __builtin_bit_cast(uint32_t, pk(pf[4][jk],  pf[5][jk]));
    uint32_t c3 = __builtin_bit_cast(uint32_t, pk(pf[6][jk],  pf[7][jk]));
    uint32_t c4 = __builtin_bit_cast(uint32_t, pk(pf[8][jk],  pf[9][jk]));
    uint32_t c5 = __builtin_bit_cast(uint32_t, pk(pf[10][jk], pf[11][jk]));
    uint32_t c6 = __builtin_bit_cast(uint32_t, pk(pf[12][jk], pf[13][jk]));
    uint32_t c7 = __builtin_bit_cast(uint32_t, pk(pf[14][jk], pf[15][jk]));
    *(uint4*)&ldsb[lds_sh(k, tok, iq * 16)]     = make_uint4(c0, c1, c2, c3);
    *(uint4*)&ldsb[lds_sh(k, tok, iq * 16 + 8)] = make_uint4(c4, c5, c6, c7);
  }
}

// ---------- main kernel ----------
__global__ __launch_bounds__(256, 4) void gbl_kernel(
    const float* __restrict__ x,     // [BN][64][16]
    const float* __restrict__ ref,   // [BN][16]
    float* __restrict__ out)         // [BN][64][16]
{
  // one buffer, two lives per tile: xT[blade][tok][i] f16, then fT[blade][tok][cc] f16
  __shared__ __align__(16) short ldsb[16 * 1024];   // 32768 B

  const int tid  = threadIdx.x;
  const int w    = tid >> 6;        // wave 0..3
  const int lane = tid & 63;
  const int n    = lane & 15;       // MFMA free-dim lane index
  const int q    = lane >> 4;       // quad
  const int br   = w >> 1, nth = w & 1;   // branch (0=prod,1=join), c-half

  // staging thread mapping: tok(4b) | kq(2b) | iq(2b)
  const int stok = tid >> 4;
  const int skq  = (tid >> 2) & 3;
  const int siq  = tid & 3;

  const int tile0 = blockIdx.x * NT;

  f32x4 pf[16];          // prefetched x (one tile's worth per thread)
  float refc[4], refn[4];

  // ---- prologue: load + stage tile 0 ----
  {
    const float* base = x + (size_t)(tile0 * 16 + stok) * 1024 + (siq * 16) * 16 + skq * 4;
    #pragma unroll
    for (int ii = 0; ii < 16; ++ii) pf[ii] = *(const f32x4*)(base + ii * 16);
    if (br == 1) {
      #pragma unroll
      for (int r = 0; r < 4; ++r) refc[r] = ref[(size_t)(tile0 * 16 + 4 * q + r) * 16 + 15];
    }
  }
  stage_write(ldsb, stok, skq, siq, pf);

  for (int it = 0; it < NT; ++it) {
    const int t0 = (tile0 + it) * 16;
    __syncthreads();                                   // [B] xT ready

    // ---- Phase 1: stage-A pre-equilins via f16 MFMA, packed-f16 results ----
    h2 pxh[16][2], pyh[16][2];
    #pragma unroll
    for (int g = 0; g < 5; ++g) {
      const short* bx = &g_wpre_h[(((br * 2 + 0) * 5 + g) * 32 + nth * 16 + n) * 64 + q * 8];
      const short* by = &g_wpre_h[(((br * 2 + 1) * 5 + g) * 32 + nth * 16 + n) * 64 + q * 8];
      h8 Bx0 = *(const h8*)(bx), Bx1 = *(const h8*)(bx + 32);
      h8 By0 = *(const h8*)(by), By1 = *(const h8*)(by + 32);
      #pragma unroll
      for (int kb = GSTART[g]; kb < GSTART[g + 1]; ++kb) {
        h8 a0 = *(const h8*)&ldsb[lds_sh(kb, n, q * 8)];
        h8 a1 = *(const h8*)&ldsb[lds_sh(kb, n, 32 + q * 8)];
        f32x4 ax = {0.f, 0.f, 0.f, 0.f};
        ax = MFMA_F16(a0, Bx0, ax, 0, 0, 0);
        ax = MFMA_F16(a1, Bx1, ax, 0, 0, 0);
        pxh[kb][0] = pk(ax[0], ax[1]);
        pxh[kb][1] = pk(ax[2], ax[3]);
        f32x4 ay = {0.f, 0.f, 0.f, 0.f};
        ay = MFMA_F16(a0, By0, ay, 0, 0, 0);
        ay = MFMA_F16(a1, By1, ay, 0, 0, 0);
        pyh[kb][0] = pk(ay[0], ay[1]);
        pyh[kb][1] = pk(ay[2], ay[3]);
      }
    }
    __syncthreads();                                   // [D] all xT reads done

    // ---- issue next tile's loads; latency hides under phase 2 + phase 3 ----
    if (it + 1 < NT) {
      const float* base = x + (size_t)((tile0 + it + 1) * 16 + stok) * 1024
                            + (siq * 16) * 16 + skq * 4;
      #pragma unroll
      for (int ii = 0; ii < 16; ++ii) pf[ii] = *(const f32x4*)(base + ii * 16);
      if (br == 1) {
        #pragma unroll
        for (int r = 0; r < 4; ++r)
          refn[r] = ref[(size_t)((tile0 + it + 1) * 16 + 4 * q + r) * 16 + 15];
      }
    }

    // ---- Phase 2: in-register bilinear (packed f16) -> fT ----
    {
      h2 rv0, rv1;
      if (br == 1) { rv0 = pk(refc[0], refc[1]); rv1 = pk(refc[2], refc[3]); }
      const int cg = w * 16 + n;
      #pragma unroll
      for (int k = 0; k < 16; ++k) {
        h2 a0 = (_Float16)0.0f, a1 = (_Float16)0.0f;
        if (br == 0) {
          #pragma unroll
          for (int m = 0; m < 16; ++m) {
            if (m < GPK.cnt[k]) {
              const int i = GPK.ti[k][m], j = GPK.tj[k][m];
              if (GPK.ts[k][m] < 0.f) { a0 -= pxh[i][0] * pyh[j][0]; a1 -= pxh[i][1] * pyh[j][1]; }
              else                    { a0 += pxh[i][0] * pyh[j][0]; a1 += pxh[i][1] * pyh[j][1]; }
            }
          }
        } else {
          #pragma unroll
          for (int m = 0; m < 16; ++m) {
            if (m < JNK.cnt[k]) {
              const int i = JNK.ti[k][m], j = JNK.tj[k][m];
              if (JNK.ts[k][m] < 0.f) { a0 -= pxh[i][0] * pyh[j][0]; a1 -= pxh[i][1] * pyh[j][1]; }
              else                    { a0 += pxh[i][0] * pyh[j][0]; a1 += pxh[i][1] * pyh[j][1]; }
            }
          }
          a0 *= rv0; a1 *= rv1;
        }
        uint32_t u0 = __builtin_bit_cast(uint32_t, a0);
        uint32_t u1 = __builtin_bit_cast(uint32_t, a1);
        ldsb[lds_sh(k, 4 * q + 0, cg)] = (short)(u0 & 0xffffu);
        ldsb[lds_sh(k, 4 * q + 1, cg)] = (short)(u0 >> 16);
        ldsb[lds_sh(k, 4 * q + 2, cg)] = (short)(u1 & 0xffffu);
        ldsb[lds_sh(k, 4 * q + 3, cg)] = (short)(u1 >> 16);
      }
    }
    __syncthreads();                                   // [F] fT ready

    // ---- Phase 3: final equilin via f16 MFMA; full D[16], 64B-contiguous stores ----
    {
      const int o = w * 16 + n;
      f32x4 D[16];
      h8 BF0, BF1;
      #pragma unroll
      for (int kb = 0; kb < 16; ++kb) {
        if (kb == 0 || kb == 1 || kb == 5 || kb == 11 || kb == 15) {   // grade boundary
          const short* bf = &g_wfin_h[(GRADE[kb] * 64 + o) * 64 + q * 8];
          BF0 = *(const h8*)(bf);
          BF1 = *(const h8*)(bf + 32);
        }
        h8 a0 = *(const h8*)&ldsb[lds_sh(kb, n, q * 8)];
        h8 a1 = *(const h8*)&ldsb[lds_sh(kb, n, 32 + q * 8)];
        f32x4 acc = {0.f, 0.f, 0.f, 0.f};
        acc = MFMA_F16(a0, BF0, acc, 0, 0, 0);
        acc = MFMA_F16(a1, BF1, acc, 0, 0, 0);
        D[kb] = acc;
      }
      #pragma unroll
      for (int r = 0; r < 4; ++r) {
        const int t = t0 + 4 * q + r;
        f32x4* op = (f32x4*)(out + (size_t)t * 1024 + o * 16);
        f32x4 s0 = {D[0][r],  D[1][r],  D[2][r],  D[3][r]};
        f32x4 s1 = {D[4][r],  D[5][r],  D[6][r],  D[7][r]};
        f32x4 s2 = {D[8][r],  D[9][r],  D[10][r], D[11][r]};
        f32x4 s3 = {D[12][r], D[13][r], D[14][r], D[15][r]};
        op[0] = s0;
        op[1] = s1;
        op[2] = s2;
        op[3] = s3;
      }
    }

    // ---- stage next tile's xT (buffer free only after all fT reads done) ----
    if (it + 1 < NT) {
      __syncthreads();                                 // [H] fT reads done
      stage_write(ldsb, stok, skq, siq, pf);
      if (br == 1) {
        #pragma unroll
        for (int r = 0; r < 4; ++r) refc[r] = refn[r];
      }
    }
  }
}

extern "C" void kernel_launch(void* const* d_in, const int* in_sizes, int n_in,
                              void* d_out, int out_size, void* d_ws, size_t ws_size,
                              hipStream_t stream) {
  const float* x   = (const float*)d_in[0];
  const float* ref = (const float*)d_in[1];
  const float* wpx = (const float*)d_in[2];
  const float* wpy = (const float*)d_in[3];
  const float* wjx = (const float*)d_in[4];
  const float* wjy = (const float*)d_in[5];
  const float* wfi = (const float*)d_in[6];

  cast_weights<<<240, 256, 0, stream>>>(wpx, wpy, wjx, wjy, wfi);
  gbl_kernel<<<GRID, 256, 0, stream>>>(x, ref, (float*)d_out);
}

// Round 6
// 271.883 us; speedup vs baseline: 1.4536x; 1.3561x over previous
//
#include <hip/hip_runtime.h>
#include <stdint.h>

// GeometricBilinearLayer: B=32,N=1024,Cin=64,Cout=64,H=32, PGA(3,0,1). f32 I/O.
// R10 = R6 structure (single tile/block, no cross-tile prefetch) + f32x4 staging.
//   R9 post-mortem: register prefetch across phases 1-3 spilled to scratch
//   (WRITE 304k, FETCH 177k = spill traffic). Fix: 16x global_load_dwordx4 per
//   thread consumed IMMEDIATELY in phase 0 (pf dies before pxh/pyh alloc) ->
//   4x wider staging bursts, zero cross-phase register cost.

#define BN 32768

typedef __attribute__((ext_vector_type(2))) _Float16 h2;   // v_pk_* operand
typedef __attribute__((ext_vector_type(8))) _Float16 h8;   // f16 MFMA fragment (4 VGPR)
typedef __attribute__((ext_vector_type(4))) float f32x4;

#define MFMA_F16 __builtin_amdgcn_mfma_f32_16x16x32_f16

__device__ __forceinline__ h2 pk(float a, float b) {
  return (h2)__builtin_amdgcn_cvt_pkrtz(a, b);   // lo = a, hi = b
}

// ---------- compile-time Clifford tables (verified by R3/R4 pass) ----------
constexpr int IDX2MASK[16] = {0,1,2,4,8,3,5,9,6,10,12,7,11,13,14,15};
constexpr int MASK2IDX[16] = {0,1,2,5,3,6,8,11,4,7,9,12,10,13,14,15};

struct MulRes { float s; int idx; };

constexpr MulRes blade_mul(int ia, int ib) {
  int arr[8] = {0,0,0,0,0,0,0,0}; int n = 0;
  for (int e = 0; e < 4; ++e) if ((IDX2MASK[ia] >> e) & 1) arr[n++] = e;
  for (int e = 0; e < 4; ++e) if ((IDX2MASK[ib] >> e) & 1) arr[n++] = e;
  float sign = 1.0f;
  bool sw = true;
  while (sw) {
    sw = false;
    for (int j = 0; j + 1 < n; ++j)
      if (arr[j] > arr[j+1]) { int t = arr[j]; arr[j] = arr[j+1]; arr[j+1] = t; sign = -sign; sw = true; }
  }
  int mask = 0; int j = 0;
  while (j < n) {
    if (j + 1 < n && arr[j] == arr[j+1]) { if (arr[j] == 0) sign = 0.0f; j += 2; }  // e0^2 = 0
    else { mask |= 1 << arr[j]; ++j; }
  }
  return MulRes{sign, MASK2IDX[mask]};
}

constexpr float dual_sign(int i) {
  return blade_mul(i, MASK2IDX[15 ^ IDX2MASK[i]]).s;
}

struct Tab { float s[16][16]; int k[16][16]; };

constexpr Tab make_gp() {
  Tab t{};
  for (int i = 0; i < 16; ++i)
    for (int j = 0; j < 16; ++j) { MulRes r = blade_mul(i, j); t.s[i][j] = r.s; t.k[i][j] = r.idx; }
  return t;
}

constexpr Tab make_join() {
  Tab t{};
  for (int i = 0; i < 16; ++i)
    for (int j = 0; j < 16; ++j) {
      int ma = 15 ^ IDX2MASK[i], mb = 15 ^ IDX2MASK[j];
      if (ma & mb) { t.s[i][j] = 0.0f; t.k[i][j] = 0; continue; }
      int ia = MASK2IDX[ma], ib = MASK2IDX[mb];
      MulRes w = blade_mul(ia, ib);
      int kk = MASK2IDX[15 ^ IDX2MASK[w.idx]];
      t.s[i][j] = dual_sign(i) * dual_sign(j) * w.s * dual_sign(kk);
      t.k[i][j] = kk;
    }
  return t;
}

constexpr Tab GPT = make_gp();
constexpr Tab JNT = make_join();
constexpr int GRADE[16] = {0,1,1,1,1,2,2,2,2,2,2,3,3,3,3,4};
constexpr int GSTART[6] = {0,1,5,11,15,16};   // blade idx is grade-ordered

// per-output-blade regrouped bilinear tables (same terms, k-major)
struct KTab { int cnt[16]; int ti[16][16]; int tj[16][16]; float ts[16][16]; };
constexpr KTab make_ktab(const Tab& t) {
  KTab b{};
  for (int i = 0; i < 16; ++i)
    for (int j = 0; j < 16; ++j) {
      float s = t.s[i][j];
      if (s != 0.f) { int k = t.k[i][j]; int m = b.cnt[k]; b.cnt[k] = m + 1;
                      b.ti[k][m] = i; b.tj[k][m] = j; b.ts[k][m] = s; }
    }
  return b;
}
constexpr KTab GPK = make_ktab(GPT);   // 192 terms, 12 per k
constexpr KTab JNK = make_ktab(JNT);   // 81 terms, <=16 per k

// ---------- LDS layout: 16 planes x 16 tok x 64 shorts, XOR-swizzled 16B chunks ----------
// short-index within plane row swizzled: s ^ (((k + tok) & 7) << 3).
__device__ __forceinline__ int lds_sh(int k, int tok, int s) {
  return k * 1024 + tok * 64 + (s ^ (((k + tok) & 7) << 3));
}

// ---------- f16 weight tables (module-scope; rewritten every launch) ----------
__device__ __align__(16) short g_wpre_h[4 * 5 * 32 * 64];   // 40960 shorts
__device__ __align__(16) short g_wfin_h[5 * 64 * 64];       // 20480 shorts

__global__ void cast_weights(const float* __restrict__ wpx, const float* __restrict__ wpy,
                             const float* __restrict__ wjx, const float* __restrict__ wjy,
                             const float* __restrict__ wf) {
  int idx = blockIdx.x * 256 + threadIdx.x;
  if (idx < 40960) {
    int which = idx / 10240, r = idx % 10240;
    const float* src = (which == 0) ? wpx : (which == 1) ? wpy : (which == 2) ? wjx : wjy;
    _Float16 h = (_Float16)src[r];
    g_wpre_h[idx] = __builtin_bit_cast(short, h);
  } else if (idx < 40960 + 20480) {
    int r = idx - 40960;
    _Float16 h = (_Float16)wf[r];
    g_wfin_h[r] = __builtin_bit_cast(short, h);
  }
}

// ---------- main kernel ----------
__global__ __launch_bounds__(256, 4) void gbl_kernel(
    const float* __restrict__ x,     // [BN][64][16]
    const float* __restrict__ ref,   // [BN][16]
    float* __restrict__ out)         // [BN][64][16]
{
  // one buffer, two lives: xT[blade][tok][i] f16, then fT[blade][tok][cc] f16
  __shared__ __align__(16) short ldsb[16 * 1024];   // 32768 B -> up to 5 blocks/CU

  const int tid  = threadIdx.x;
  const int w    = tid >> 6;        // wave 0..3
  const int lane = tid & 63;
  const int n    = lane & 15;       // MFMA free-dim lane index
  const int q    = lane >> 4;       // quad
  const int t0   = blockIdx.x * 16;
  const int br   = w >> 1, nth = w & 1;   // branch (0=prod,1=join), c-half

  // ref pseudoscalar prefetch for join waves (hide latency under phase 0/1)
  float refv[4];
  if (br == 1) {
    #pragma unroll
    for (int r = 0; r < 4; ++r) refv[r] = ref[(size_t)(t0 + 4 * q + r) * 16 + 15];
  }

  // ---- Phase 0: stage x-tile -> xT (transposed, f16, swizzled) ----
  // thread (tok, kq, iq): 16x dwordx4 burst (x[t0+tok][iq*16+ii][kq*4..+3]),
  // consumed immediately -> pf dies before phase 1 register allocation.
  {
    const int stok = tid >> 4;
    const int skq  = (tid >> 2) & 3;
    const int siq  = tid & 3;
    const float* base = x + (size_t)(t0 + stok) * 1024 + (siq * 16) * 16 + skq * 4;
    f32x4 pf[16];
    #pragma unroll
    for (int ii = 0; ii < 16; ++ii) pf[ii] = *(const f32x4*)(base + ii * 16);
    #pragma unroll
    for (int jk = 0; jk < 4; ++jk) {
      const int k = skq * 4 + jk;
      uint32_t c0 = __builtin_bit_cast(uint32_t, pk(pf[0][jk],  pf[1][jk]));
      uint32_t c1 = __builtin_bit_cast(uint32_t, pk(pf[2][jk],  pf[3][jk]));
      uint32_t c2 = __builtin_bit_cast(uint32_t, pk(pf[4][jk],  pf[5][jk]));
      uint32_t c3 = __builtin_bit_cast(uint32_t, pk(pf[6][jk],  pf[7][jk]));
      uint32_t c4 = __builtin_bit_cast(uint32_t, pk(pf[8][jk],  pf[9][jk]));
      uint32_t c5 = __builtin_bit_cast(uint32_t, pk(pf[10][jk], pf[11][jk]));
      uint32_t c6 = __builtin_bit_cast(uint32_t, pk(pf[12][jk], pf[13][jk]));
      uint32_t c7 = __builtin_bit_cast(uint32_t, pk(pf[14][jk], pf[15][jk]));
      *(uint4*)&ldsb[lds_sh(k, stok, siq * 16)]     = make_uint4(c0, c1, c2, c3);
      *(uint4*)&ldsb[lds_sh(k, stok, siq * 16 + 8)] = make_uint4(c4, c5, c6, c7);
    }
  }
  __syncthreads();

  // ---- Phase 1: stage-A pre-equilins via f16 MFMA, packed-f16 results ----
  // wave w: c_global = w*16 + n. X and Y sets share the A-fragment loads.
  h2 pxh[16][2], pyh[16][2];   // 64 regs packed
  {
    #pragma unroll
    for (int g = 0; g < 5; ++g) {
      const short* bx = &g_wpre_h[(((br * 2 + 0) * 5 + g) * 32 + nth * 16 + n) * 64 + q * 8];
      const short* by = &g_wpre_h[(((br * 2 + 1) * 5 + g) * 32 + nth * 16 + n) * 64 + q * 8];
      h8 Bx0 = *(const h8*)(bx), Bx1 = *(const h8*)(bx + 32);
      h8 By0 = *(const h8*)(by), By1 = *(const h8*)(by + 32);
      #pragma unroll
      for (int kb = GSTART[g]; kb < GSTART[g + 1]; ++kb) {
        h8 a0 = *(const h8*)&ldsb[lds_sh(kb, n, q * 8)];
        h8 a1 = *(const h8*)&ldsb[lds_sh(kb, n, 32 + q * 8)];
        f32x4 ax = {0.f, 0.f, 0.f, 0.f};
        ax = MFMA_F16(a0, Bx0, ax, 0, 0, 0);
        ax = MFMA_F16(a1, Bx1, ax, 0, 0, 0);
        pxh[kb][0] = pk(ax[0], ax[1]);
        pxh[kb][1] = pk(ax[2], ax[3]);
        f32x4 ay = {0.f, 0.f, 0.f, 0.f};
        ay = MFMA_F16(a0, By0, ay, 0, 0, 0);
        ay = MFMA_F16(a1, By1, ay, 0, 0, 0);
        pyh[kb][0] = pk(ay[0], ay[1]);
        pyh[kb][1] = pk(ay[2], ay[3]);
      }
    }
  }
  __syncthreads();   // all xT reads done; ldsb becomes fT

  // ---- Phase 2: in-register bilinear (packed f16) -> fT ----
  // lane holds px/py for c = w*16 + n, token pairs (4q+0,4q+1) / (4q+2,4q+3)
  {
    h2 rv0, rv1;
    if (br == 1) { rv0 = pk(refv[0], refv[1]); rv1 = pk(refv[2], refv[3]); }
    const int cg = w * 16 + n;
    #pragma unroll
    for (int k = 0; k < 16; ++k) {
      h2 a0 = (_Float16)0.0f, a1 = (_Float16)0.0f;
      if (br == 0) {
        #pragma unroll
        for (int m = 0; m < 16; ++m) {
          if (m < GPK.cnt[k]) {
            const int i = GPK.ti[k][m], j = GPK.tj[k][m];
            if (GPK.ts[k][m] < 0.f) { a0 -= pxh[i][0] * pyh[j][0]; a1 -= pxh[i][1] * pyh[j][1]; }
            else                    { a0 += pxh[i][0] * pyh[j][0]; a1 += pxh[i][1] * pyh[j][1]; }
          }
        }
      } else {
        #pragma unroll
        for (int m = 0; m < 16; ++m) {
          if (m < JNK.cnt[k]) {
            const int i = JNK.ti[k][m], j = JNK.tj[k][m];
            if (JNK.ts[k][m] < 0.f) { a0 -= pxh[i][0] * pyh[j][0]; a1 -= pxh[i][1] * pyh[j][1]; }
            else                    { a0 += pxh[i][0] * pyh[j][0]; a1 += pxh[i][1] * pyh[j][1]; }
          }
        }
        a0 *= rv0; a1 *= rv1;
      }
      uint32_t u0 = __builtin_bit_cast(uint32_t, a0);
      uint32_t u1 = __builtin_bit_cast(uint32_t, a1);
      ldsb[lds_sh(k, 4 * q + 0, cg)] = (short)(u0 & 0xffffu);
      ldsb[lds_sh(k, 4 * q + 1, cg)] = (short)(u0 >> 16);
      ldsb[lds_sh(k, 4 * q + 2, cg)] = (short)(u1 & 0xffffu);
      ldsb[lds_sh(k, 4 * q + 3, cg)] = (short)(u1 >> 16);
    }
  }
  __syncthreads();

  // ---- Phase 3: final equilin via f16 MFMA; full D[16], 64B-contiguous stores ----
  {
    const int o = w * 16 + n;
    f32x4 D[16];
    h8 BF0, BF1;
    #pragma unroll
    for (int kb = 0; kb < 16; ++kb) {
      if (kb == 0 || kb == 1 || kb == 5 || kb == 11 || kb == 15) {   // grade boundary
        const short* bf = &g_wfin_h[(GRADE[kb] * 64 + o) * 64 + q * 8];
        BF0 = *(const h8*)(bf);
        BF1 = *(const h8*)(bf + 32);
      }
      h8 a0 = *(const h8*)&ldsb[lds_sh(kb, n, q * 8)];
      h8 a1 = *(const h8*)&ldsb[lds_sh(kb, n, 32 + q * 8)];
      f32x4 acc = {0.f, 0.f, 0.f, 0.f};
      acc = MFMA_F16(a0, BF0, acc, 0, 0, 0);
      acc = MFMA_F16(a1, BF1, acc, 0, 0, 0);
      D[kb] = acc;
    }

    #pragma unroll
    for (int r = 0; r < 4; ++r) {
      const int t = t0 + 4 * q + r;
      f32x4* op = (f32x4*)(out + (size_t)t * 1024 + o * 16);
      f32x4 s0 = {D[0][r],  D[1][r],  D[2][r],  D[3][r]};
      f32x4 s1 = {D[4][r],  D[5][r],  D[6][r],  D[7][r]};
      f32x4 s2 = {D[8][r],  D[9][r],  D[10][r], D[11][r]};
      f32x4 s3 = {D[12][r], D[13][r], D[14][r], D[15][r]};
      op[0] = s0;
      op[1] = s1;
      op[2] = s2;
      op[3] = s3;
    }
  }
}

extern "C" void kernel_launch(void* const* d_in, const int* in_sizes, int n_in,
                              void* d_out, int out_size, void* d_ws, size_t ws_size,
                              hipStream_t stream) {
  const float* x   = (const float*)d_in[0];
  const float* ref = (const float*)d_in[1];
  const float* wpx = (const float*)d_in[2];
  const float* wpy = (const float*)d_in[3];
  const float* wjx = (const float*)d_in[4];
  const float* wjy = (const float*)d_in[5];
  const float* wfi = (const float*)d_in[6];

  cast_weights<<<240, 256, 0, stream>>>(wpx, wpy, wjx, wjy, wfi);
  gbl_kernel<<<BN / 16, 256, 0, stream>>>(x, ref, (float*)d_out);
}